// Round 9
// baseline (663.297 us; speedup 1.0000x reference)
//
#include <hip/hip_runtime.h>
#include <hip/hip_bf16.h>

#define N_NODES 100000
#define N_EDGES 1600000
#define IN_FEA 128
#define HIDDEN 128
#define RANK 64

#define NBUCK 391          // ceil(N_NODES/256): bucket b = nodes [b*256, b*256+256)
#define C_BLOCKS 1024      // hist blocks
#define EPB 1563           // edges per hist block
#define S_BLOCKS 256       // binscatter blocks (chunk = 4 hist rows)
#define CHUNK_W (EPB * 4)  // 6252 edges per scatter chunk
#define GEMM1_BLOCKS 1563  // ceil(N_NODES / 64)

#define AGG_BLOCKS 782     // 2 blocks per bucket; each block owns 128 nodes
#define CAPE 4096          // LDS eidx capacity per half-bucket (mean 2048, sd 45)

// ---------------- helpers ----------------

__device__ __forceinline__ void fma4(float4& a, float s, const float4& b) {
    a.x = fmaf(s, b.x, a.x);
    a.y = fmaf(s, b.y, a.y);
    a.z = fmaf(s, b.z, a.z);
    a.w = fmaf(s, b.w, a.w);
}

__device__ __forceinline__ unsigned short f2bf_rne(float f) {
    unsigned u = __float_as_uint(f);
    u += 0x7fffu + ((u >> 16) & 1u);
    return (unsigned short)(u >> 16);
}

// low bf16 of a packed uint -> float (1 VALU: lshl)
__device__ __forceinline__ float bfu_lo(unsigned u) {
    return __uint_as_float(u << 16);
}
// high bf16 of a packed uint -> float (1 VALU: and)
__device__ __forceinline__ float bfu_hi(unsigned u) {
    return __uint_as_float(u & 0xffff0000u);
}

// ---------------- fused GEMM1 + bucket histogram ----------------
// blocks [0, GEMM1_BLOCKS): h_bf = bf16(x @ W), 64 nodes/block.
// blocks [GEMM1_BLOCKS, +C_BLOCKS): per-block bucket histogram (EPB edges each).

__global__ __launch_bounds__(256) void gemm1_hist_kernel(const float* __restrict__ x,
                                                         const float* __restrict__ W,
                                                         unsigned short* __restrict__ hb,
                                                         const int* __restrict__ dst,
                                                         int* __restrict__ bhist,
                                                         int* __restrict__ blockhist) {
    __shared__ float Wl[IN_FEA * RANK];  // 32 KB (hist aliases first 1.6 KB)
    int t = threadIdx.x;

    if (blockIdx.x >= GEMM1_BLOCKS) {
        int* hist = (int*)Wl;
        int b = blockIdx.x - GEMM1_BLOCKS;
        for (int i = t; i < NBUCK; i += 256) hist[i] = 0;
        __syncthreads();
        int b0 = b * EPB;
        int b1 = min(b0 + EPB, N_EDGES);
        for (int e = b0 + t; e < b1; e += 256)
            atomicAdd(&hist[dst[e] >> 8], 1);
        __syncthreads();
        for (int i = t; i < NBUCK; i += 256) {
            int c = hist[i];
            blockhist[b * NBUCK + i] = c;
            if (c) atomicAdd(&bhist[i], c);
        }
        return;
    }

    for (int i = t; i < IN_FEA * RANK; i += 256) Wl[i] = W[i];
    __syncthreads();

    int r0 = (t & 15) * 4;
    int n0 = blockIdx.x * 64 + (t >> 4) * 4;
    const float4* x0 = (const float4*)(x + (long)min(n0 + 0, N_NODES - 1) * IN_FEA);
    const float4* x1 = (const float4*)(x + (long)min(n0 + 1, N_NODES - 1) * IN_FEA);
    const float4* x2 = (const float4*)(x + (long)min(n0 + 2, N_NODES - 1) * IN_FEA);
    const float4* x3 = (const float4*)(x + (long)min(n0 + 3, N_NODES - 1) * IN_FEA);
    float4 a0 = {0.f, 0.f, 0.f, 0.f}, a1 = a0, a2 = a0, a3 = a0;
    for (int k4 = 0; k4 < IN_FEA / 4; ++k4) {
        float4 v0 = x0[k4], v1 = x1[k4], v2 = x2[k4], v3 = x3[k4];
        int kb = k4 * 4;
        float4 w0 = *(const float4*)&Wl[(kb + 0) * RANK + r0];
        float4 w1 = *(const float4*)&Wl[(kb + 1) * RANK + r0];
        float4 w2 = *(const float4*)&Wl[(kb + 2) * RANK + r0];
        float4 w3 = *(const float4*)&Wl[(kb + 3) * RANK + r0];
        fma4(a0, v0.x, w0); fma4(a0, v0.y, w1); fma4(a0, v0.z, w2); fma4(a0, v0.w, w3);
        fma4(a1, v1.x, w0); fma4(a1, v1.y, w1); fma4(a1, v1.z, w2); fma4(a1, v1.w, w3);
        fma4(a2, v2.x, w0); fma4(a2, v2.y, w1); fma4(a2, v2.z, w2); fma4(a2, v2.w, w3);
        fma4(a3, v3.x, w0); fma4(a3, v3.y, w1); fma4(a3, v3.z, w2); fma4(a3, v3.w, w3);
    }
    float4 accs[4] = {a0, a1, a2, a3};
#pragma unroll
    for (int i = 0; i < 4; ++i) {
        if (n0 + i < N_NODES) {
            ushort4 o;
            o.x = f2bf_rne(accs[i].x); o.y = f2bf_rne(accs[i].y);
            o.z = f2bf_rne(accs[i].z); o.w = f2bf_rne(accs[i].w);
            *(ushort4*)(hb + (n0 + i) * RANK + r0) = o;
        }
    }
}

// ---------------- CSR build ----------------

__global__ void bucket_scan_kernel(const int* __restrict__ bhist,
                                   int* __restrict__ bucket_offs,
                                   int* __restrict__ bucket_cursor) {
    __shared__ int sd[512];
    int t = threadIdx.x;
    int v = (t < NBUCK) ? bhist[t] : 0;
    sd[t] = v;
    __syncthreads();
    for (int off = 1; off < 512; off <<= 1) {
        int a = 0;
        if (t >= off) a = sd[t - off];
        __syncthreads();
        sd[t] += a;
        __syncthreads();
    }
    if (t < NBUCK) {
        int excl = sd[t] - v;
        bucket_offs[t] = excl;
        bucket_cursor[t] = excl;
    }
    if (t == 0) bucket_offs[NBUCK] = N_EDGES;
}

// Fat-chunk scatter on the full chip: 256 blocks x 1024 threads.
__global__ __launch_bounds__(1024) void binscatter_kernel(const int* __restrict__ src,
                                                          const int* __restrict__ dst,
                                                          const int* __restrict__ blockhist,
                                                          int* __restrict__ bucket_cursor,
                                                          unsigned* __restrict__ pairs) {
    __shared__ int wbase[NBUCK];
    __shared__ int cur[NBUCK];
    int t = threadIdx.x;
    int b = blockIdx.x;
    if (t < NBUCK) {
        int s = 0;
#pragma unroll
        for (int k = 0; k < 4; ++k)
            s += blockhist[(4 * b + k) * NBUCK + t];
        wbase[t] = s ? atomicAdd(&bucket_cursor[t], s) : 0;
        cur[t] = 0;
    }
    __syncthreads();
    int e0 = b * CHUNK_W;
    int e1 = min(e0 + CHUNK_W, N_EDGES);
    for (int e = e0 + t; e < e1; e += 1024) {
        int d = dst[e];
        int s = src[e];
        int bk = d >> 8;
        int lp = atomicAdd(&cur[bk], 1);
        pairs[wbase[bk] + lp] = ((unsigned)s << 8) | (unsigned)(d & 255);
    }
}

// ---------------- fused within-bucket sort + aggregation + GEMM2 ----------------
// R17: bucket_build eliminated. Each agg block sorts its HALF-BUCKET's pairs in
// LDS (count -> scan -> scatter; the 64-lane-scattered stores that made
// bucket_build transaction-limited now hit LDS instead of L2), then runs the
// proven R11 product+epilogue reading the edge list from LDS. Global eidx/offs
// arrays and one full kernel pass disappear.
// 782 blocks = 2/bucket (bit 7 of local key selects half): keeps LDS at 61 KB
// (2 blocks/CU, wave-capped) AND ~3 block-generations/CU of wave turnover for
// the latency-bound hb gather. pairs lives in ws (NOT d_out) -> no aliasing
// with out writes. CAPE=4096 vs half-bucket mean 2048 (sd 45): overflow-guarded.

__global__ __launch_bounds__(1024) void agg_gemm_kernel(const unsigned short* __restrict__ hb,
                                                        const float* __restrict__ norm,
                                                        const float* __restrict__ V,
                                                        const unsigned* __restrict__ pairs,
                                                        const int* __restrict__ bucket_offs,
                                                        float* __restrict__ out) {
    __shared__ float VL[HIDDEN * 68];      // 34,816 B
    __shared__ float pls[16][2][64];       // 8,192 B
    __shared__ int eidx_lds[CAPE];         // 16,384 B
    __shared__ int dcnt[128];              // 512 B
    __shared__ int sdv[128];               // 512 B
    __shared__ int curv[128];              // 512 B
    int t = threadIdx.x;
    {
        const float4* V4 = (const float4*)V;
#pragma unroll
        for (int k = 0; k < 2; ++k) {
            int i4 = t + 1024 * k;
            float4 v = V4[i4];
            int el = i4 << 2;
            *(float4*)&VL[(el >> 6) * 68 + (el & 63)] = v;
        }
    }
    int bkt = blockIdx.x >> 1;
    unsigned halfb = blockIdx.x & 1;       // which 128-node half of the bucket
    int e0 = bucket_offs[bkt], e1 = bucket_offs[bkt + 1];
    if (t < 128) dcnt[t] = 0;
    __syncthreads();

    // count this half's nodes
    for (int i = e0 + t; i < e1; i += 1024) {
        unsigned r = pairs[i];
        if (((r >> 7) & 1u) == halfb) atomicAdd(&dcnt[r & 127u], 1);
    }
    __syncthreads();

    // exclusive scan over 128 counters (masked; all threads hit barriers)
    int v = 0;
    if (t < 128) { v = dcnt[t]; sdv[t] = v; }
    __syncthreads();
    for (int off = 1; off < 128; off <<= 1) {
        int a = 0;
        if (t >= off && t < 128) a = sdv[t - off];
        __syncthreads();
        if (t < 128) sdv[t] += a;
        __syncthreads();
    }
    if (t < 128) curv[t] = sdv[t] - v;
    __syncthreads();

    // scatter src into LDS edge list, grouped by local node
    for (int i = e0 + t; i < e1; i += 1024) {
        unsigned r = pairs[i];
        if (((r >> 7) & 1u) == halfb) {
            int lp = atomicAdd(&curv[r & 127u], 1);
            if (lp < CAPE) eidx_lds[lp] = (int)(r >> 8);
        }
    }
    __syncthreads();

    int wave = t >> 6, lane = t & 63;
    int half = lane >> 5;      // which edge of the pair this lane serves
    int l32 = lane & 31;       // rank-pair index: ranks {2*l32, 2*l32+1}
    int nbase = blockIdx.x * 128;
    const unsigned* hb2 = (const unsigned*)hb; // hb2[s*32 + l32] = packed ranks {2*l32, 2*l32+1}

#pragma clang loop unroll(disable)
    for (int rp = 0; rp < 4; ++rp) {
#pragma unroll
        for (int i = 0; i < 2; ++i) {
            int ln = wave * 8 + rp * 2 + i;     // local node 0..127
            int node = nbase + ln;
            int beg = sdv[ln] - dcnt[ln];
            int end = sdv[ln];

            float plo = 1.0f, phi = 1.0f;
            for (int c = beg; c < end; c += 64) {
                int n = min(64, end - c);
                int sidx = (c + lane < end) ? eidx_lds[c + lane] : 0;
                int j = 0;
                // 8 loads in flight = 16 edges
                for (; j + 16 <= n; j += 16) {
                    int s0 = __shfl(sidx, j + 0  + half);
                    int s1 = __shfl(sidx, j + 2  + half);
                    int s2 = __shfl(sidx, j + 4  + half);
                    int s3 = __shfl(sidx, j + 6  + half);
                    int s4 = __shfl(sidx, j + 8  + half);
                    int s5 = __shfl(sidx, j + 10 + half);
                    int s6 = __shfl(sidx, j + 12 + half);
                    int s7 = __shfl(sidx, j + 14 + half);
                    unsigned u0 = hb2[(s0 << 5) | l32];
                    unsigned u1 = hb2[(s1 << 5) | l32];
                    unsigned u2 = hb2[(s2 << 5) | l32];
                    unsigned u3 = hb2[(s3 << 5) | l32];
                    unsigned u4 = hb2[(s4 << 5) | l32];
                    unsigned u5 = hb2[(s5 << 5) | l32];
                    unsigned u6 = hb2[(s6 << 5) | l32];
                    unsigned u7 = hb2[(s7 << 5) | l32];
                    plo *= ((bfu_lo(u0) * bfu_lo(u1)) * (bfu_lo(u2) * bfu_lo(u3))) *
                           ((bfu_lo(u4) * bfu_lo(u5)) * (bfu_lo(u6) * bfu_lo(u7)));
                    phi *= ((bfu_hi(u0) * bfu_hi(u1)) * (bfu_hi(u2) * bfu_hi(u3))) *
                           ((bfu_hi(u4) * bfu_hi(u5)) * (bfu_hi(u6) * bfu_hi(u7)));
                }
                // 4 loads = 8 edges
                for (; j + 8 <= n; j += 8) {
                    int s0 = __shfl(sidx, j + 0 + half);
                    int s1 = __shfl(sidx, j + 2 + half);
                    int s2 = __shfl(sidx, j + 4 + half);
                    int s3 = __shfl(sidx, j + 6 + half);
                    unsigned u0 = hb2[(s0 << 5) | l32];
                    unsigned u1 = hb2[(s1 << 5) | l32];
                    unsigned u2 = hb2[(s2 << 5) | l32];
                    unsigned u3 = hb2[(s3 << 5) | l32];
                    plo *= (bfu_lo(u0) * bfu_lo(u1)) * (bfu_lo(u2) * bfu_lo(u3));
                    phi *= (bfu_hi(u0) * bfu_hi(u1)) * (bfu_hi(u2) * bfu_hi(u3));
                }
                // pair tail (2 edges / iter; odd edge masked to identity on upper half)
                for (; j < n; j += 2) {
                    int jj = j + half;             // lane n has sidx=0 -> safe addr
                    int s = __shfl(sidx, jj);
                    unsigned u = hb2[(s << 5) | l32];
                    float alo = bfu_lo(u), ahi = bfu_hi(u);
                    if (jj >= n) { alo = 1.0f; ahi = 1.0f; }
                    plo *= alo;
                    phi *= ahi;
                }
            }
            // merge edge-parity halves
            plo *= __shfl_xor(plo, 32);
            phi *= __shfl_xor(phi, 32);

            if (lane < 32) {
                float nrm = (node < N_NODES) ? norm[node] : 0.f;
                float2 o;
                o.x = plo * nrm;
                o.y = phi * nrm;
                *(float2*)&pls[wave][i][l32 * 2] = o;
            }
            // wave-private slab: no barrier needed
        }

        // epilogue for this round's 2 nodes (R11 structure, V read once serves both)
        int n0 = nbase + wave * 8 + rp * 2;
        const float4* rA = (const float4*)&VL[lane * 68];
        const float4* rB = (const float4*)&VL[(lane + 64) * 68];
        const float4* p0 = (const float4*)pls[wave][0];
        const float4* p1 = (const float4*)pls[wave][1];
        float aA0 = 0.f, aB0 = 0.f, aA1 = 0.f, aB1 = 0.f;
#pragma unroll
        for (int q = 0; q < 16; ++q) {
            float4 va = rA[q];
            float4 vb = rB[q];
            float4 pp;
            pp = p0[q];   // broadcast read
            aA0 = fmaf(pp.x, va.x, fmaf(pp.y, va.y, fmaf(pp.z, va.z, fmaf(pp.w, va.w, aA0))));
            aB0 = fmaf(pp.x, vb.x, fmaf(pp.y, vb.y, fmaf(pp.z, vb.z, fmaf(pp.w, vb.w, aB0))));
            pp = p1[q];
            aA1 = fmaf(pp.x, va.x, fmaf(pp.y, va.y, fmaf(pp.z, va.z, fmaf(pp.w, va.w, aA1))));
            aB1 = fmaf(pp.x, vb.x, fmaf(pp.y, vb.y, fmaf(pp.z, vb.z, fmaf(pp.w, vb.w, aB1))));
        }
        if (n0 < N_NODES) {
            out[n0 * HIDDEN + lane]      = aA0;
            out[n0 * HIDDEN + 64 + lane] = aB0;
        }
        if (n0 + 1 < N_NODES) {
            out[(n0 + 1) * HIDDEN + lane]      = aA1;
            out[(n0 + 1) * HIDDEN + 64 + lane] = aB1;
        }
    }
}

// ---------------- launch ----------------

extern "C" void kernel_launch(void* const* d_in, const int* in_sizes, int n_in,
                              void* d_out, int out_size, void* d_ws, size_t ws_size,
                              hipStream_t stream) {
    const float* x    = (const float*)d_in[0];
    const float* norm = (const float*)d_in[1];
    const float* W    = (const float*)d_in[2];
    const float* V    = (const float*)d_in[3];
    const int*   src  = (const int*)d_in[4];
    const int*   dst  = (const int*)d_in[5];
    float* out = (float*)d_out;

    // workspace layout (ws): hb (bf16), pairs (replaces old offs+eidx), buckets
    unsigned short* hb = (unsigned short*)d_ws;               // N*RANK bf16 (12.8 MB)
    unsigned* pairs    = (unsigned*)(hb + (long)N_NODES * RANK);  // E uint32 (6.4 MB)
    int*   bhist       = (int*)(pairs + N_EDGES);             // NBUCK
    int*   bucket_offs = bhist + NBUCK;                       // NBUCK+1
    int*   bucket_cur  = bucket_offs + NBUCK + 1;             // NBUCK

    // scratch inside d_out (consumed by binscatter BEFORE agg writes out):
    int* blockhist = (int*)d_out + 2097152;                   // at +8 MB: C_BLOCKS*NBUCK ints

    hipMemsetAsync(bhist, 0, NBUCK * sizeof(int), stream);
    gemm1_hist_kernel<<<GEMM1_BLOCKS + C_BLOCKS, 256, 0, stream>>>(x, W, hb, dst, bhist, blockhist);
    bucket_scan_kernel<<<1, 512, 0, stream>>>(bhist, bucket_offs, bucket_cur);
    binscatter_kernel<<<S_BLOCKS, 1024, 0, stream>>>(src, dst, blockhist, bucket_cur, pairs);
    agg_gemm_kernel<<<AGG_BLOCKS, 1024, 0, stream>>>(hb, norm, V, pairs, bucket_offs, out);
}

// Round 10
// 360.943 us; speedup vs baseline: 1.8377x; 1.8377x over previous
//
#include <hip/hip_runtime.h>
#include <hip/hip_bf16.h>

#define N_NODES 100000
#define N_EDGES 1600000
#define IN_FEA 128
#define HIDDEN 128
#define RANK 64

#define NBUCK 391          // ceil(N_NODES/256): bucket b = nodes [b*256, b*256+256)
#define C_BLOCKS 1024      // hist blocks
#define EPB 1563           // edges per hist block
#define S_BLOCKS 256       // binscatter blocks (chunk = 4 hist rows)
#define CHUNK_W (EPB * 4)  // 6252 edges per scatter chunk
#define GEMM1_BLOCKS 1563  // ceil(N_NODES / 64)

#define NPW 2              // nodes per wave in agg_gemm (V-read amortization)
#define AGG_BLOCKS 3125    // N_NODES / (16 waves * NPW) exactly

// ---------------- helpers ----------------

__device__ __forceinline__ void fma4(float4& a, float s, const float4& b) {
    a.x = fmaf(s, b.x, a.x);
    a.y = fmaf(s, b.y, a.y);
    a.z = fmaf(s, b.z, a.z);
    a.w = fmaf(s, b.w, a.w);
}

__device__ __forceinline__ unsigned short f2bf_rne(float f) {
    unsigned u = __float_as_uint(f);
    u += 0x7fffu + ((u >> 16) & 1u);
    return (unsigned short)(u >> 16);
}

// low bf16 of a packed uint -> float (1 VALU: lshl)
__device__ __forceinline__ float bfu_lo(unsigned u) {
    return __uint_as_float(u << 16);
}
// high bf16 of a packed uint -> float (1 VALU: and)
__device__ __forceinline__ float bfu_hi(unsigned u) {
    return __uint_as_float(u & 0xffff0000u);
}

__device__ __forceinline__ float rdlane(float v, int l) {
    return __uint_as_float(__builtin_amdgcn_readlane(__float_as_uint(v), l));
}

// ---------------- fused GEMM1 + bucket histogram + (last block) bucket scan ----------------
// blocks [0, GEMM1_BLOCKS): h_bf = bf16(x @ W), 64 nodes/block.
// blocks [GEMM1_BLOCKS, +C_BLOCKS): per-block bucket histogram (EPB edges each).
// R18: the LAST hist block to finish (done-counter handshake, no spinning ->
// no deadlock) performs the 391-wide bucket scan inline, deleting the
// bucket_scan launch + inter-kernel gap.

__global__ __launch_bounds__(256) void gemm1_hist_kernel(const float* __restrict__ x,
                                                         const float* __restrict__ W,
                                                         unsigned short* __restrict__ hb,
                                                         const int* __restrict__ dst,
                                                         int* __restrict__ bhist,
                                                         int* __restrict__ blockhist,
                                                         int* __restrict__ done,
                                                         int* __restrict__ bucket_offs,
                                                         int* __restrict__ bucket_cursor,
                                                         int* __restrict__ offs) {
    __shared__ float Wl[IN_FEA * RANK];  // 32 KB (hist + scan alias it)
    __shared__ int lastf;
    int t = threadIdx.x;

    if (blockIdx.x >= GEMM1_BLOCKS) {
        int* hist = (int*)Wl;
        int b = blockIdx.x - GEMM1_BLOCKS;
        for (int i = t; i < NBUCK; i += 256) hist[i] = 0;
        __syncthreads();
        int b0 = b * EPB;
        int b1 = min(b0 + EPB, N_EDGES);
        for (int e = b0 + t; e < b1; e += 256)
            atomicAdd(&hist[dst[e] >> 8], 1);
        __syncthreads();
        for (int i = t; i < NBUCK; i += 256) {
            int c = hist[i];
            blockhist[b * NBUCK + i] = c;
            if (c) atomicAdd(&bhist[i], c);
        }
        // ---- last-done block performs the bucket scan ----
        __threadfence();                       // release our bhist adds
        if (t == 0) lastf = (atomicAdd(done, 1) == C_BLOCKS - 1) ? 1 : 0;
        __syncthreads();
        if (!lastf) return;
        __threadfence();                       // acquire all blocks' bhist adds
        int* sa = hist + 512;                  // ping
        int* sb = sa + 512;                    // pong (fits: 391+512+512 < 8192 ints)
        for (int i = t; i < NBUCK; i += 256) sa[i] = bhist[i];
        __syncthreads();
        int* pin = sa; int* pout = sb;
        for (int off = 1; off < NBUCK; off <<= 1) {   // Hillis-Steele inclusive scan
            for (int i = t; i < NBUCK; i += 256)
                pout[i] = (i >= off) ? pin[i] + pin[i - off] : pin[i];
            __syncthreads();
            int* tmp = pin; pin = pout; pout = tmp;
        }
        for (int i = t; i < NBUCK; i += 256) {
            int excl = pin[i] - bhist[i];
            bucket_offs[i] = excl;
            bucket_cursor[i] = excl;
        }
        if (t == 0) {
            bucket_offs[NBUCK] = N_EDGES;
            offs[N_NODES] = N_EDGES;
        }
        return;
    }

    for (int i = t; i < IN_FEA * RANK; i += 256) Wl[i] = W[i];
    __syncthreads();

    int r0 = (t & 15) * 4;
    int n0 = blockIdx.x * 64 + (t >> 4) * 4;
    const float4* x0 = (const float4*)(x + (long)min(n0 + 0, N_NODES - 1) * IN_FEA);
    const float4* x1 = (const float4*)(x + (long)min(n0 + 1, N_NODES - 1) * IN_FEA);
    const float4* x2 = (const float4*)(x + (long)min(n0 + 2, N_NODES - 1) * IN_FEA);
    const float4* x3 = (const float4*)(x + (long)min(n0 + 3, N_NODES - 1) * IN_FEA);
    float4 a0 = {0.f, 0.f, 0.f, 0.f}, a1 = a0, a2 = a0, a3 = a0;
    for (int k4 = 0; k4 < IN_FEA / 4; ++k4) {
        float4 v0 = x0[k4], v1 = x1[k4], v2 = x2[k4], v3 = x3[k4];
        int kb = k4 * 4;
        float4 w0 = *(const float4*)&Wl[(kb + 0) * RANK + r0];
        float4 w1 = *(const float4*)&Wl[(kb + 1) * RANK + r0];
        float4 w2 = *(const float4*)&Wl[(kb + 2) * RANK + r0];
        float4 w3 = *(const float4*)&Wl[(kb + 3) * RANK + r0];
        fma4(a0, v0.x, w0); fma4(a0, v0.y, w1); fma4(a0, v0.z, w2); fma4(a0, v0.w, w3);
        fma4(a1, v1.x, w0); fma4(a1, v1.y, w1); fma4(a1, v1.z, w2); fma4(a1, v1.w, w3);
        fma4(a2, v2.x, w0); fma4(a2, v2.y, w1); fma4(a2, v2.z, w2); fma4(a2, v2.w, w3);
        fma4(a3, v3.x, w0); fma4(a3, v3.y, w1); fma4(a3, v3.z, w2); fma4(a3, v3.w, w3);
    }
    float4 accs[4] = {a0, a1, a2, a3};
#pragma unroll
    for (int i = 0; i < 4; ++i) {
        if (n0 + i < N_NODES) {
            ushort4 o;
            o.x = f2bf_rne(accs[i].x); o.y = f2bf_rne(accs[i].y);
            o.z = f2bf_rne(accs[i].z); o.w = f2bf_rne(accs[i].w);
            *(ushort4*)(hb + (n0 + i) * RANK + r0) = o;
        }
    }
}

// ---------------- CSR build ----------------

// Fat-chunk scatter on the full chip: 256 blocks x 1024 threads; int2 edge
// reads (all chunk lengths and starts are even -> aligned, no tail).
__global__ __launch_bounds__(1024) void binscatter_kernel(const int* __restrict__ src,
                                                          const int* __restrict__ dst,
                                                          const int* __restrict__ blockhist,
                                                          int* __restrict__ bucket_cursor,
                                                          unsigned* __restrict__ pairs) {
    __shared__ int wbase[NBUCK];
    __shared__ int cur[NBUCK];
    int t = threadIdx.x;
    int b = blockIdx.x;
    if (t < NBUCK) {
        int s = 0;
#pragma unroll
        for (int k = 0; k < 4; ++k)
            s += blockhist[(4 * b + k) * NBUCK + t];
        wbase[t] = s ? atomicAdd(&bucket_cursor[t], s) : 0;
        cur[t] = 0;
    }
    __syncthreads();
    int e0 = b * CHUNK_W;
    int e1 = min(e0 + CHUNK_W, N_EDGES);
    for (int e = e0 + t * 2; e < e1; e += 2048) {
        int2 d2 = *(const int2*)&dst[e];
        int2 s2 = *(const int2*)&src[e];
        int bk0 = d2.x >> 8;
        int lp0 = atomicAdd(&cur[bk0], 1);
        pairs[wbase[bk0] + lp0] = ((unsigned)s2.x << 8) | (unsigned)(d2.x & 255);
        int bk1 = d2.y >> 8;
        int lp1 = atomicAdd(&cur[bk1], 1);
        pairs[wbase[bk1] + lp1] = ((unsigned)s2.y << 8) | (unsigned)(d2.y & 255);
    }
}

// 1024 threads per bucket; edge loops stride 1024, 256-wide scan masked.
__global__ __launch_bounds__(1024) void bucket_build_kernel(const unsigned* __restrict__ pairs,
                                                            const int* __restrict__ bucket_offs,
                                                            int* __restrict__ offs,
                                                            int* __restrict__ eidx) {
    __shared__ int dcnt[256];
    __shared__ int sd[256];
    __shared__ int cur[256];
    int b = blockIdx.x, t = threadIdx.x;
    int base = bucket_offs[b], end = bucket_offs[b + 1];
    if (t < 256) dcnt[t] = 0;
    __syncthreads();
    for (int i = base + t; i < end; i += 1024)
        atomicAdd(&dcnt[pairs[i] & 255u], 1);
    __syncthreads();
    int v = 0;
    if (t < 256) { v = dcnt[t]; sd[t] = v; }
    __syncthreads();
    for (int off = 1; off < 256; off <<= 1) {
        int a = 0;
        if (t >= off && t < 256) a = sd[t - off];
        __syncthreads();
        if (t < 256) sd[t] += a;
        __syncthreads();
    }
    if (t < 256) {
        int excl = sd[t] - v;
        int node = b * 256 + t;
        if (node < N_NODES) offs[node] = base + excl;
        cur[t] = excl;
    }
    __syncthreads();
    for (int i = base + t; i < end; i += 1024) {
        unsigned r = pairs[i];
        int lp = atomicAdd(&cur[r & 255u], 1);
        eidx[base + lp] = (int)(r >> 8);
    }
}

// ---------------- fused aggregation + GEMM2 ----------------
// R18 epilogue: READLANE broadcast of p. After the parity merge, lane k<32
// already holds p[2k](plo), p[2k+1](phi); fold norm in (bit-identical values)
// and broadcast via v_readlane (compile-time lane -> SGPR -> v_fmac w/ SGPR
// operand). Deletes the pls LDS round-trip: per-node epilogue LDS b128 reads
// 32 -> 16 (the V reads only), LDS 43 -> 35 KB. Same FMA tree -> bit-identical.
// Keep: NPW=2, 16 waves x 1024, 3125 short-lived blocks (L2-warm gathers).
// LESSON (R10/R12/R17): any growth of live state past ~60 VGPR at 1024 thr
// spills catastrophically. This change REMOVES live state (no pls pointers).

__global__ __launch_bounds__(1024) void agg_gemm_kernel(const unsigned short* __restrict__ hb,
                                                        const float* __restrict__ norm,
                                                        const float* __restrict__ V,
                                                        const int* __restrict__ offs,
                                                        const int* __restrict__ eidx,
                                                        float* __restrict__ out) {
    __shared__ float VL[HIDDEN * 68];      // 34,816 B
    int t = threadIdx.x;
    {
        const float4* V4 = (const float4*)V;
#pragma unroll
        for (int k = 0; k < 2; ++k) {
            int i4 = t + 1024 * k;
            float4 v = V4[i4];
            int el = i4 << 2;
            *(float4*)&VL[(el >> 6) * 68 + (el & 63)] = v;
        }
    }
    __syncthreads();

    int wave = t >> 6, lane = t & 63;
    int half = lane >> 5;      // which edge of the pair this lane serves
    int l32 = lane & 31;       // rank-pair index: ranks {2*l32, 2*l32+1}
    int nb = (blockIdx.x * 16 + wave) * NPW;   // first node of this wave
    const unsigned* hb2 = (const unsigned*)hb; // hb2[s*32 + l32] = packed ranks {2*l32, 2*l32+1}

    float plo0, phi0, plo1, phi1;
#pragma unroll
    for (int i = 0; i < NPW; ++i) {
        int node = nb + i;
        int beg = offs[node], end = offs[node + 1];

        float plo = 1.0f, phi = 1.0f;
        for (int c = beg; c < end; c += 64) {
            int n = min(64, end - c);
            int sidx = (c + lane < end) ? eidx[c + lane] : 0;
            int j = 0;
            // 8 loads in flight = 16 edges
            for (; j + 16 <= n; j += 16) {
                int s0 = __shfl(sidx, j + 0  + half);
                int s1 = __shfl(sidx, j + 2  + half);
                int s2 = __shfl(sidx, j + 4  + half);
                int s3 = __shfl(sidx, j + 6  + half);
                int s4 = __shfl(sidx, j + 8  + half);
                int s5 = __shfl(sidx, j + 10 + half);
                int s6 = __shfl(sidx, j + 12 + half);
                int s7 = __shfl(sidx, j + 14 + half);
                unsigned u0 = hb2[(s0 << 5) | l32];
                unsigned u1 = hb2[(s1 << 5) | l32];
                unsigned u2 = hb2[(s2 << 5) | l32];
                unsigned u3 = hb2[(s3 << 5) | l32];
                unsigned u4 = hb2[(s4 << 5) | l32];
                unsigned u5 = hb2[(s5 << 5) | l32];
                unsigned u6 = hb2[(s6 << 5) | l32];
                unsigned u7 = hb2[(s7 << 5) | l32];
                plo *= ((bfu_lo(u0) * bfu_lo(u1)) * (bfu_lo(u2) * bfu_lo(u3))) *
                       ((bfu_lo(u4) * bfu_lo(u5)) * (bfu_lo(u6) * bfu_lo(u7)));
                phi *= ((bfu_hi(u0) * bfu_hi(u1)) * (bfu_hi(u2) * bfu_hi(u3))) *
                       ((bfu_hi(u4) * bfu_hi(u5)) * (bfu_hi(u6) * bfu_hi(u7)));
            }
            // 4 loads = 8 edges
            for (; j + 8 <= n; j += 8) {
                int s0 = __shfl(sidx, j + 0 + half);
                int s1 = __shfl(sidx, j + 2 + half);
                int s2 = __shfl(sidx, j + 4 + half);
                int s3 = __shfl(sidx, j + 6 + half);
                unsigned u0 = hb2[(s0 << 5) | l32];
                unsigned u1 = hb2[(s1 << 5) | l32];
                unsigned u2 = hb2[(s2 << 5) | l32];
                unsigned u3 = hb2[(s3 << 5) | l32];
                plo *= (bfu_lo(u0) * bfu_lo(u1)) * (bfu_lo(u2) * bfu_lo(u3));
                phi *= (bfu_hi(u0) * bfu_hi(u1)) * (bfu_hi(u2) * bfu_hi(u3));
            }
            // pair tail (2 edges / iter; odd edge masked to identity on upper half)
            for (; j < n; j += 2) {
                int jj = j + half;                 // lane n has sidx=0 -> safe addr
                int s = __shfl(sidx, jj);
                unsigned u = hb2[(s << 5) | l32];
                float alo = bfu_lo(u), ahi = bfu_hi(u);
                if (jj >= n) { alo = 1.0f; ahi = 1.0f; }
                plo *= alo;
                phi *= ahi;
            }
        }
        // merge edge-parity halves: lane l and lane l^32 hold the same rank pair
        plo *= __shfl_xor(plo, 32);
        phi *= __shfl_xor(phi, 32);

        // fold norm in now (identical arithmetic to the old pls-store path)
        float nrm = norm[node];
        plo *= nrm;
        phi *= nrm;
        if (i == 0) { plo0 = plo; phi0 = phi; } else { plo1 = plo; phi1 = phi; }
    }

    // epilogue: V read once serves NPW=2 nodes; p broadcast via readlane (SGPR),
    // zero LDS traffic for p. Same fma nesting as before -> bit-identical.
    const float4* rA = (const float4*)&VL[lane * 68];
    const float4* rB = (const float4*)&VL[(lane + 64) * 68];
    float aA0 = 0.f, aB0 = 0.f, aA1 = 0.f, aB1 = 0.f;
#pragma unroll
    for (int q = 0; q < 16; ++q) {
        float4 va = rA[q];
        float4 vb = rB[q];
        float px = rdlane(plo0, 2 * q);
        float py = rdlane(phi0, 2 * q);
        float pz = rdlane(plo0, 2 * q + 1);
        float pw = rdlane(phi0, 2 * q + 1);
        aA0 = fmaf(px, va.x, fmaf(py, va.y, fmaf(pz, va.z, fmaf(pw, va.w, aA0))));
        aB0 = fmaf(px, vb.x, fmaf(py, vb.y, fmaf(pz, vb.z, fmaf(pw, vb.w, aB0))));
        px = rdlane(plo1, 2 * q);
        py = rdlane(phi1, 2 * q);
        pz = rdlane(plo1, 2 * q + 1);
        pw = rdlane(phi1, 2 * q + 1);
        aA1 = fmaf(px, va.x, fmaf(py, va.y, fmaf(pz, va.z, fmaf(pw, va.w, aA1))));
        aB1 = fmaf(px, vb.x, fmaf(py, vb.y, fmaf(pz, vb.z, fmaf(pw, vb.w, aB1))));
    }
    out[(nb + 0) * HIDDEN + lane]      = aA0;
    out[(nb + 0) * HIDDEN + 64 + lane] = aB0;
    out[(nb + 1) * HIDDEN + lane]      = aA1;
    out[(nb + 1) * HIDDEN + 64 + lane] = aB1;
}

// ---------------- launch ----------------

extern "C" void kernel_launch(void* const* d_in, const int* in_sizes, int n_in,
                              void* d_out, int out_size, void* d_ws, size_t ws_size,
                              hipStream_t stream) {
    const float* x    = (const float*)d_in[0];
    const float* norm = (const float*)d_in[1];
    const float* W    = (const float*)d_in[2];
    const float* V    = (const float*)d_in[3];
    const int*   src  = (const int*)d_in[4];
    const int*   dst  = (const int*)d_in[5];
    float* out = (float*)d_out;

    // workspace layout (ws): hb (bf16), offs, eidx, bucket arrays, done ctr
    unsigned short* hb = (unsigned short*)d_ws;              // N*RANK bf16 (12.8 MB)
    int*   offs        = (int*)(hb + (long)N_NODES * RANK);  // N+1
    int*   eidx        = offs + N_NODES + 1;                 // E
    int*   bhist       = eidx + N_EDGES;                     // NBUCK
    int*   done        = bhist + NBUCK;                      // 1 (zeroed with bhist)
    int*   bucket_offs = done + 1;                           // NBUCK+1
    int*   bucket_cur  = bucket_offs + NBUCK + 1;            // NBUCK

    // scratch inside d_out (dead until agg_gemm writes out):
    unsigned* pairs    = (unsigned*)d_out;                   // E uint32 (6.4 MB)
    int*     blockhist = (int*)d_out + 2097152;              // at +8 MB: C_BLOCKS*NBUCK ints

    hipMemsetAsync(bhist, 0, (NBUCK + 1) * sizeof(int), stream);
    gemm1_hist_kernel<<<GEMM1_BLOCKS + C_BLOCKS, 256, 0, stream>>>(
        x, W, hb, dst, bhist, blockhist, done, bucket_offs, bucket_cur, offs);
    binscatter_kernel<<<S_BLOCKS, 1024, 0, stream>>>(src, dst, blockhist, bucket_cur, pairs);
    bucket_build_kernel<<<NBUCK, 1024, 0, stream>>>(pairs, bucket_offs, offs, eidx);
    agg_gemm_kernel<<<AGG_BLOCKS, 1024, 0, stream>>>(hb, norm, V, offs, eidx, out);
}

// Round 11
// 252.428 us; speedup vs baseline: 2.6277x; 1.4299x over previous
//
#include <hip/hip_runtime.h>
#include <hip/hip_bf16.h>

#define N_NODES 100000
#define N_EDGES 1600000
#define IN_FEA 128
#define HIDDEN 128
#define RANK 64

#define NBUCK 391          // ceil(N_NODES/256): bucket b = nodes [b*256, b*256+256)
#define C_BLOCKS 1024      // hist blocks
#define EPB 1563           // edges per hist block
#define S_BLOCKS 256       // binscatter blocks (chunk = 4 hist rows)
#define CHUNK_W (EPB * 4)  // 6252 edges per scatter chunk
#define GEMM1_BLOCKS 1563  // ceil(N_NODES / 64)

#define NPW 2              // nodes per wave in agg_gemm (V-read amortization)
#define AGG_BLOCKS 3125    // N_NODES / (16 waves * NPW) exactly

// ---------------- helpers ----------------

__device__ __forceinline__ void fma4(float4& a, float s, const float4& b) {
    a.x = fmaf(s, b.x, a.x);
    a.y = fmaf(s, b.y, a.y);
    a.z = fmaf(s, b.z, a.z);
    a.w = fmaf(s, b.w, a.w);
}

__device__ __forceinline__ unsigned short f2bf_rne(float f) {
    unsigned u = __float_as_uint(f);
    u += 0x7fffu + ((u >> 16) & 1u);
    return (unsigned short)(u >> 16);
}

// low bf16 of a packed uint -> float (1 VALU: lshl)
__device__ __forceinline__ float bfu_lo(unsigned u) {
    return __uint_as_float(u << 16);
}
// high bf16 of a packed uint -> float (1 VALU: and)
__device__ __forceinline__ float bfu_hi(unsigned u) {
    return __uint_as_float(u & 0xffff0000u);
}

__device__ __forceinline__ float rdlane(float v, int l) {
    return __uint_as_float(__builtin_amdgcn_readlane(__float_as_uint(v), l));
}

// ---------------- fused GEMM1 + bucket histogram (R16 form: NO device fences) ----------------
// blocks [0, GEMM1_BLOCKS): h_bf = bf16(x @ W), 64 nodes/block.
// blocks [GEMM1_BLOCKS, +C_BLOCKS): per-block bucket histogram (EPB edges each).
// LESSON (R18): a __threadfence() per hist block (1024 device-scope release
// fences = 1024 L2 writebacks on non-coherent-XCD hardware) serialized the
// whole kernel (172 us, VALUBusy 8%). Keep the 1-block scan as its own launch.

__global__ __launch_bounds__(256) void gemm1_hist_kernel(const float* __restrict__ x,
                                                         const float* __restrict__ W,
                                                         unsigned short* __restrict__ hb,
                                                         const int* __restrict__ dst,
                                                         int* __restrict__ bhist,
                                                         int* __restrict__ blockhist) {
    __shared__ float Wl[IN_FEA * RANK];  // 32 KB (hist aliases first 1.6 KB)
    int t = threadIdx.x;

    if (blockIdx.x >= GEMM1_BLOCKS) {
        int* hist = (int*)Wl;
        int b = blockIdx.x - GEMM1_BLOCKS;
        for (int i = t; i < NBUCK; i += 256) hist[i] = 0;
        __syncthreads();
        int b0 = b * EPB;
        int b1 = min(b0 + EPB, N_EDGES);
        for (int e = b0 + t; e < b1; e += 256)
            atomicAdd(&hist[dst[e] >> 8], 1);
        __syncthreads();
        for (int i = t; i < NBUCK; i += 256) {
            int c = hist[i];
            blockhist[b * NBUCK + i] = c;
            if (c) atomicAdd(&bhist[i], c);
        }
        return;
    }

    for (int i = t; i < IN_FEA * RANK; i += 256) Wl[i] = W[i];
    __syncthreads();

    int r0 = (t & 15) * 4;
    int n0 = blockIdx.x * 64 + (t >> 4) * 4;
    const float4* x0 = (const float4*)(x + (long)min(n0 + 0, N_NODES - 1) * IN_FEA);
    const float4* x1 = (const float4*)(x + (long)min(n0 + 1, N_NODES - 1) * IN_FEA);
    const float4* x2 = (const float4*)(x + (long)min(n0 + 2, N_NODES - 1) * IN_FEA);
    const float4* x3 = (const float4*)(x + (long)min(n0 + 3, N_NODES - 1) * IN_FEA);
    float4 a0 = {0.f, 0.f, 0.f, 0.f}, a1 = a0, a2 = a0, a3 = a0;
    for (int k4 = 0; k4 < IN_FEA / 4; ++k4) {
        float4 v0 = x0[k4], v1 = x1[k4], v2 = x2[k4], v3 = x3[k4];
        int kb = k4 * 4;
        float4 w0 = *(const float4*)&Wl[(kb + 0) * RANK + r0];
        float4 w1 = *(const float4*)&Wl[(kb + 1) * RANK + r0];
        float4 w2 = *(const float4*)&Wl[(kb + 2) * RANK + r0];
        float4 w3 = *(const float4*)&Wl[(kb + 3) * RANK + r0];
        fma4(a0, v0.x, w0); fma4(a0, v0.y, w1); fma4(a0, v0.z, w2); fma4(a0, v0.w, w3);
        fma4(a1, v1.x, w0); fma4(a1, v1.y, w1); fma4(a1, v1.z, w2); fma4(a1, v1.w, w3);
        fma4(a2, v2.x, w0); fma4(a2, v2.y, w1); fma4(a2, v2.z, w2); fma4(a2, v2.w, w3);
        fma4(a3, v3.x, w0); fma4(a3, v3.y, w1); fma4(a3, v3.z, w2); fma4(a3, v3.w, w3);
    }
    float4 accs[4] = {a0, a1, a2, a3};
#pragma unroll
    for (int i = 0; i < 4; ++i) {
        if (n0 + i < N_NODES) {
            ushort4 o;
            o.x = f2bf_rne(accs[i].x); o.y = f2bf_rne(accs[i].y);
            o.z = f2bf_rne(accs[i].z); o.w = f2bf_rne(accs[i].w);
            *(ushort4*)(hb + (n0 + i) * RANK + r0) = o;
        }
    }
}

// ---------------- CSR build ----------------

__global__ void bucket_scan_kernel(const int* __restrict__ bhist,
                                   int* __restrict__ bucket_offs,
                                   int* __restrict__ bucket_cursor,
                                   int* __restrict__ offs) {
    __shared__ int sd[512];
    int t = threadIdx.x;
    int v = (t < NBUCK) ? bhist[t] : 0;
    sd[t] = v;
    __syncthreads();
    for (int off = 1; off < 512; off <<= 1) {
        int a = 0;
        if (t >= off) a = sd[t - off];
        __syncthreads();
        sd[t] += a;
        __syncthreads();
    }
    if (t < NBUCK) {
        int excl = sd[t] - v;
        bucket_offs[t] = excl;
        bucket_cursor[t] = excl;
    }
    if (t == 0) {
        bucket_offs[NBUCK] = N_EDGES;
        offs[N_NODES] = N_EDGES;
    }
}

// Fat-chunk scatter on the full chip: 256 blocks x 1024 threads; int2 edge
// reads (all chunk lengths and starts are even -> aligned, no tail).
__global__ __launch_bounds__(1024) void binscatter_kernel(const int* __restrict__ src,
                                                          const int* __restrict__ dst,
                                                          const int* __restrict__ blockhist,
                                                          int* __restrict__ bucket_cursor,
                                                          unsigned* __restrict__ pairs) {
    __shared__ int wbase[NBUCK];
    __shared__ int cur[NBUCK];
    int t = threadIdx.x;
    int b = blockIdx.x;
    if (t < NBUCK) {
        int s = 0;
#pragma unroll
        for (int k = 0; k < 4; ++k)
            s += blockhist[(4 * b + k) * NBUCK + t];
        wbase[t] = s ? atomicAdd(&bucket_cursor[t], s) : 0;
        cur[t] = 0;
    }
    __syncthreads();
    int e0 = b * CHUNK_W;
    int e1 = min(e0 + CHUNK_W, N_EDGES);
    for (int e = e0 + t * 2; e < e1; e += 2048) {
        int2 d2 = *(const int2*)&dst[e];
        int2 s2 = *(const int2*)&src[e];
        int bk0 = d2.x >> 8;
        int lp0 = atomicAdd(&cur[bk0], 1);
        pairs[wbase[bk0] + lp0] = ((unsigned)s2.x << 8) | (unsigned)(d2.x & 255);
        int bk1 = d2.y >> 8;
        int lp1 = atomicAdd(&cur[bk1], 1);
        pairs[wbase[bk1] + lp1] = ((unsigned)s2.y << 8) | (unsigned)(d2.y & 255);
    }
}

// 1024 threads per bucket; edge loops stride 1024, 256-wide scan masked.
__global__ __launch_bounds__(1024) void bucket_build_kernel(const unsigned* __restrict__ pairs,
                                                            const int* __restrict__ bucket_offs,
                                                            int* __restrict__ offs,
                                                            int* __restrict__ eidx) {
    __shared__ int dcnt[256];
    __shared__ int sd[256];
    __shared__ int cur[256];
    int b = blockIdx.x, t = threadIdx.x;
    int base = bucket_offs[b], end = bucket_offs[b + 1];
    if (t < 256) dcnt[t] = 0;
    __syncthreads();
    for (int i = base + t; i < end; i += 1024)
        atomicAdd(&dcnt[pairs[i] & 255u], 1);
    __syncthreads();
    int v = 0;
    if (t < 256) { v = dcnt[t]; sd[t] = v; }
    __syncthreads();
    for (int off = 1; off < 256; off <<= 1) {
        int a = 0;
        if (t >= off && t < 256) a = sd[t - off];
        __syncthreads();
        if (t < 256) sd[t] += a;
        __syncthreads();
    }
    if (t < 256) {
        int excl = sd[t] - v;
        int node = b * 256 + t;
        if (node < N_NODES) offs[node] = base + excl;
        cur[t] = excl;
    }
    __syncthreads();
    for (int i = base + t; i < end; i += 1024) {
        unsigned r = pairs[i];
        int lp = atomicAdd(&cur[r & 255u], 1);
        eidx[base + lp] = (int)(r >> 8);
    }
}

// ---------------- fused aggregation + GEMM2 (readlane epilogue) ----------------
// Epilogue: READLANE broadcast of p. After the parity merge, lane k<32 already
// holds p[2k](plo), p[2k+1](phi); fold norm in (bit-identical values) and
// broadcast via v_readlane (compile-time lane -> SGPR -> v_fmac w/ SGPR
// operand). Deletes the pls LDS round-trip: per-node epilogue LDS b128 reads
// 32 -> 16 (V reads only), LDS 43 -> 35 KB. Same FMA tree -> bit-identical.
// Keep: NPW=2, 16 waves x 1024, 3125 short-lived blocks (L2-warm gathers).
// LESSON (R10/R12/R17): live state past ~60 VGPR at 1024 thr spills; this
// epilogue REMOVES live state vs R16 (no pls pointers).

__global__ __launch_bounds__(1024) void agg_gemm_kernel(const unsigned short* __restrict__ hb,
                                                        const float* __restrict__ norm,
                                                        const float* __restrict__ V,
                                                        const int* __restrict__ offs,
                                                        const int* __restrict__ eidx,
                                                        float* __restrict__ out) {
    __shared__ float VL[HIDDEN * 68];      // 34,816 B
    int t = threadIdx.x;
    {
        const float4* V4 = (const float4*)V;
#pragma unroll
        for (int k = 0; k < 2; ++k) {
            int i4 = t + 1024 * k;
            float4 v = V4[i4];
            int el = i4 << 2;
            *(float4*)&VL[(el >> 6) * 68 + (el & 63)] = v;
        }
    }
    __syncthreads();

    int wave = t >> 6, lane = t & 63;
    int half = lane >> 5;      // which edge of the pair this lane serves
    int l32 = lane & 31;       // rank-pair index: ranks {2*l32, 2*l32+1}
    int nb = (blockIdx.x * 16 + wave) * NPW;   // first node of this wave
    const unsigned* hb2 = (const unsigned*)hb; // hb2[s*32 + l32] = packed ranks {2*l32, 2*l32+1}

    float plo0, phi0, plo1, phi1;
#pragma unroll
    for (int i = 0; i < NPW; ++i) {
        int node = nb + i;
        int beg = offs[node], end = offs[node + 1];

        float plo = 1.0f, phi = 1.0f;
        for (int c = beg; c < end; c += 64) {
            int n = min(64, end - c);
            int sidx = (c + lane < end) ? eidx[c + lane] : 0;
            int j = 0;
            // 8 loads in flight = 16 edges
            for (; j + 16 <= n; j += 16) {
                int s0 = __shfl(sidx, j + 0  + half);
                int s1 = __shfl(sidx, j + 2  + half);
                int s2 = __shfl(sidx, j + 4  + half);
                int s3 = __shfl(sidx, j + 6  + half);
                int s4 = __shfl(sidx, j + 8  + half);
                int s5 = __shfl(sidx, j + 10 + half);
                int s6 = __shfl(sidx, j + 12 + half);
                int s7 = __shfl(sidx, j + 14 + half);
                unsigned u0 = hb2[(s0 << 5) | l32];
                unsigned u1 = hb2[(s1 << 5) | l32];
                unsigned u2 = hb2[(s2 << 5) | l32];
                unsigned u3 = hb2[(s3 << 5) | l32];
                unsigned u4 = hb2[(s4 << 5) | l32];
                unsigned u5 = hb2[(s5 << 5) | l32];
                unsigned u6 = hb2[(s6 << 5) | l32];
                unsigned u7 = hb2[(s7 << 5) | l32];
                plo *= ((bfu_lo(u0) * bfu_lo(u1)) * (bfu_lo(u2) * bfu_lo(u3))) *
                       ((bfu_lo(u4) * bfu_lo(u5)) * (bfu_lo(u6) * bfu_lo(u7)));
                phi *= ((bfu_hi(u0) * bfu_hi(u1)) * (bfu_hi(u2) * bfu_hi(u3))) *
                       ((bfu_hi(u4) * bfu_hi(u5)) * (bfu_hi(u6) * bfu_hi(u7)));
            }
            // 4 loads = 8 edges
            for (; j + 8 <= n; j += 8) {
                int s0 = __shfl(sidx, j + 0 + half);
                int s1 = __shfl(sidx, j + 2 + half);
                int s2 = __shfl(sidx, j + 4 + half);
                int s3 = __shfl(sidx, j + 6 + half);
                unsigned u0 = hb2[(s0 << 5) | l32];
                unsigned u1 = hb2[(s1 << 5) | l32];
                unsigned u2 = hb2[(s2 << 5) | l32];
                unsigned u3 = hb2[(s3 << 5) | l32];
                plo *= (bfu_lo(u0) * bfu_lo(u1)) * (bfu_lo(u2) * bfu_lo(u3));
                phi *= (bfu_hi(u0) * bfu_hi(u1)) * (bfu_hi(u2) * bfu_hi(u3));
            }
            // pair tail (2 edges / iter; odd edge masked to identity on upper half)
            for (; j < n; j += 2) {
                int jj = j + half;                 // lane n has sidx=0 -> safe addr
                int s = __shfl(sidx, jj);
                unsigned u = hb2[(s << 5) | l32];
                float alo = bfu_lo(u), ahi = bfu_hi(u);
                if (jj >= n) { alo = 1.0f; ahi = 1.0f; }
                plo *= alo;
                phi *= ahi;
            }
        }
        // merge edge-parity halves: lane l and lane l^32 hold the same rank pair
        plo *= __shfl_xor(plo, 32);
        phi *= __shfl_xor(phi, 32);

        // fold norm in now (identical arithmetic to the old pls-store path)
        float nrm = norm[node];
        plo *= nrm;
        phi *= nrm;
        if (i == 0) { plo0 = plo; phi0 = phi; } else { plo1 = plo; phi1 = phi; }
    }

    // epilogue: V read once serves NPW=2 nodes; p broadcast via readlane (SGPR),
    // zero LDS traffic for p. Same fma nesting as before -> bit-identical.
    const float4* rA = (const float4*)&VL[lane * 68];
    const float4* rB = (const float4*)&VL[(lane + 64) * 68];
    float aA0 = 0.f, aB0 = 0.f, aA1 = 0.f, aB1 = 0.f;
#pragma unroll
    for (int q = 0; q < 16; ++q) {
        float4 va = rA[q];
        float4 vb = rB[q];
        float px = rdlane(plo0, 2 * q);
        float py = rdlane(phi0, 2 * q);
        float pz = rdlane(plo0, 2 * q + 1);
        float pw = rdlane(phi0, 2 * q + 1);
        aA0 = fmaf(px, va.x, fmaf(py, va.y, fmaf(pz, va.z, fmaf(pw, va.w, aA0))));
        aB0 = fmaf(px, vb.x, fmaf(py, vb.y, fmaf(pz, vb.z, fmaf(pw, vb.w, aB0))));
        px = rdlane(plo1, 2 * q);
        py = rdlane(phi1, 2 * q);
        pz = rdlane(plo1, 2 * q + 1);
        pw = rdlane(phi1, 2 * q + 1);
        aA1 = fmaf(px, va.x, fmaf(py, va.y, fmaf(pz, va.z, fmaf(pw, va.w, aA1))));
        aB1 = fmaf(px, vb.x, fmaf(py, vb.y, fmaf(pz, vb.z, fmaf(pw, vb.w, aB1))));
    }
    out[(nb + 0) * HIDDEN + lane]      = aA0;
    out[(nb + 0) * HIDDEN + 64 + lane] = aB0;
    out[(nb + 1) * HIDDEN + lane]      = aA1;
    out[(nb + 1) * HIDDEN + 64 + lane] = aB1;
}

// ---------------- launch ----------------

extern "C" void kernel_launch(void* const* d_in, const int* in_sizes, int n_in,
                              void* d_out, int out_size, void* d_ws, size_t ws_size,
                              hipStream_t stream) {
    const float* x    = (const float*)d_in[0];
    const float* norm = (const float*)d_in[1];
    const float* W    = (const float*)d_in[2];
    const float* V    = (const float*)d_in[3];
    const int*   src  = (const int*)d_in[4];
    const int*   dst  = (const int*)d_in[5];
    float* out = (float*)d_out;

    // workspace layout (ws): hb (bf16), offs, eidx, small bucket arrays
    unsigned short* hb = (unsigned short*)d_ws;              // N*RANK bf16 (12.8 MB)
    int*   offs        = (int*)(hb + (long)N_NODES * RANK);  // N+1
    int*   eidx        = offs + N_NODES + 1;                 // E
    int*   bhist       = eidx + N_EDGES;                     // NBUCK
    int*   bucket_offs = bhist + NBUCK;                      // NBUCK+1
    int*   bucket_cur  = bucket_offs + NBUCK + 1;            // NBUCK

    // scratch inside d_out (dead until agg_gemm writes out):
    unsigned* pairs    = (unsigned*)d_out;                   // E uint32 (6.4 MB)
    int*     blockhist = (int*)d_out + 2097152;              // at +8 MB: C_BLOCKS*NBUCK ints

    hipMemsetAsync(bhist, 0, NBUCK * sizeof(int), stream);
    gemm1_hist_kernel<<<GEMM1_BLOCKS + C_BLOCKS, 256, 0, stream>>>(x, W, hb, dst, bhist, blockhist);
    bucket_scan_kernel<<<1, 512, 0, stream>>>(bhist, bucket_offs, bucket_cur, offs);
    binscatter_kernel<<<S_BLOCKS, 1024, 0, stream>>>(src, dst, blockhist, bucket_cur, pairs);
    bucket_build_kernel<<<NBUCK, 1024, 0, stream>>>(pairs, bucket_offs, offs, eidx);
    agg_gemm_kernel<<<AGG_BLOCKS, 1024, 0, stream>>>(hb, norm, V, offs, eidx, out);
}